// Round 10
// baseline (236.241 us; speedup 1.0000x reference)
//
#include <hip/hip_runtime.h>
#include <hip/hip_bf16.h>

#define BB 8
#define SS 2048
#define DD 256
#define CC 32
#define HH 4
#define HD 64
#define MTOT (BB*SS)   // 16384 tokens

using bf16    = __hip_bfloat16;
using short8  = __attribute__((ext_vector_type(8))) short;
using short4v = __attribute__((ext_vector_type(4))) short;
using floatx4 = __attribute__((ext_vector_type(4))) float;

#if __has_builtin(__builtin_amdgcn_mfma_f32_16x16x16_bf16)
  #define MFMA_PV16(a,b,c) __builtin_amdgcn_mfma_f32_16x16x16_bf16(a,b,c,0,0,0)
  #define HAVE_PV16 1
#elif __has_builtin(__builtin_amdgcn_mfma_f32_16x16x16bf16_1k)
  #define MFMA_PV16(a,b,c) __builtin_amdgcn_mfma_f32_16x16x16bf16_1k(a,b,c,0,0,0)
  #define HAVE_PV16 1
#else
  #define HAVE_PV16 0
#endif

#if __has_builtin(__builtin_amdgcn_global_load_lds)
  #define HAVE_GLL 1
#else
  #define HAVE_GLL 0
#endif

#if __has_builtin(__builtin_amdgcn_exp2f)
  #define EXP2F(x) __builtin_amdgcn_exp2f(x)
#else
  #define EXP2F(x) exp2f(x)
#endif

__device__ inline float bf2f(unsigned short u) {
    union { unsigned int i; float f; } v; v.i = ((unsigned int)u) << 16; return v.f;
}
__device__ inline unsigned short f2bfbits(float f) {
    bf16 h = __float2bfloat16(f);
    return __builtin_bit_cast(unsigned short, h);
}
// 3-input max; clang fuses nested fmaxf to v_max3_f32 on gfx9+
__device__ inline float max3f(float a, float b, float c) {
    return fmaxf(fmaxf(a, b), c);
}

// --------------------------------------------------------------------------
#define N_X    (MTOT*DD)
#define N_COND (MTOT*CC)
#define N_WQW  (DD*DD)
#define N_WQB  (DD)
#define N_WVW  (DD*DD)
#define N_WVB  (DD)
#define N_WKW  (CC*DD*DD)
#define N_WKB  (CC*DD)
#define N_WOW  (DD*DD)
#define N_WOB  (DD)
#define P0 0
#define P1 (P0+N_X)
#define P2 (P1+N_COND)
#define P3 (P2+N_WQW)
#define P4 (P3+N_WQB)
#define P5 (P4+N_WVW)
#define P6 (P5+N_WVB)
#define P7 (P6+N_WKW)
#define P8 (P7+N_WKB)
#define P9 (P8+N_WOW)
#define PTOT (P9+N_WOB)

// --------------------------------------------------------------------------
// Fused dtype-detect + conversion. Each block self-detects from 256 sampled
// words of x (fp32 N(0,1): ~all in [1e-4,1e4]; bf16-pair-garbage: ~none).
// Block 0 publishes the flag for the final GEMM's epilogue.
// --------------------------------------------------------------------------
__global__ void convert_all(const void* s0, const void* s1, const void* s2,
                            const void* s3, const void* s4, const void* s5,
                            const void* s6, const void* s7, const void* s8,
                            const void* s9, bf16* dst, int* flagw)
{
    __shared__ int cnts[4];
    {
        const float* xf = (const float*)s0;
        float v = fabsf(xf[threadIdx.x]);
        bool ok = (v == v) && v > 1e-4f && v < 1e4f;
        unsigned long long m = __ballot(ok);
        if ((threadIdx.x & 63) == 0) cnts[threadIdx.x >> 6] = __popcll(m);
    }
    __syncthreads();
    const bool f32 = (cnts[0] + cnts[1] + cnts[2] + cnts[3]) > 128;
    if (blockIdx.x == 0 && threadIdx.x == 0) *flagw = f32 ? 1 : 0;

    size_t i = ((size_t)blockIdx.x * 256 + threadIdx.x) * 8;
    const size_t stride = (size_t)gridDim.x * 256 * 8;
    for (; i < (size_t)PTOT; i += stride) {
        const void* src; size_t off;
        if      (i < P1) { src = s0; off = i - P0; }
        else if (i < P2) { src = s1; off = i - P1; }
        else if (i < P3) { src = s2; off = i - P2; }
        else if (i < P4) { src = s3; off = i - P3; }
        else if (i < P5) { src = s4; off = i - P4; }
        else if (i < P6) { src = s5; off = i - P5; }
        else if (i < P7) { src = s6; off = i - P6; }
        else if (i < P8) { src = s7; off = i - P7; }
        else if (i < P9) { src = s8; off = i - P8; }
        else             { src = s9; off = i - P9; }
        if (f32) {
            const float* s = (const float*)src + off;
            float4 a = *(const float4*)(s);
            float4 b = *(const float4*)(s + 4);
            __align__(16) unsigned short t[8];
            t[0] = f2bfbits(a.x); t[1] = f2bfbits(a.y);
            t[2] = f2bfbits(a.z); t[3] = f2bfbits(a.w);
            t[4] = f2bfbits(b.x); t[5] = f2bfbits(b.y);
            t[6] = f2bfbits(b.z); t[7] = f2bfbits(b.w);
            *(uint4*)(dst + i) = *(const uint4*)t;
        } else {
            *(uint4*)(dst + i) = *(const uint4*)((const unsigned short*)src + off);
        }
    }
}

// ---------------------------------------------------------------------------
// Shared staging helper (classkey-validated): stages a 64-row x 256-col bf16
// tile into linear LDS via width-16 global_load_lds, with XOR chunk swizzle
// on the GLOBAL source (rule #21: linear dst + inv-swizzled src + swizzled
// read). LDS[row][b] = global[row][b ^ (row&7)] in 8-element blocks.
// ---------------------------------------------------------------------------
__device__ __forceinline__ void stage_ws4(const bf16* __restrict__ Wc,
                                          unsigned short* wsbuf, int w, int lane)
{
    #pragma unroll
    for (int i = 0; i < 8; ++i) {
        int rr = w * 16 + i * 2 + (lane >> 5);
        int cs = (lane & 31) ^ (rr & 7);
        const bf16* src = Wc + (size_t)rr * DD + cs * 8;
        unsigned short* dst = wsbuf + (size_t)(w * 16 + i * 2) * DD;
#if HAVE_GLL
        __builtin_amdgcn_global_load_lds(
            (const __attribute__((address_space(1))) void*)src,
            (__attribute__((address_space(3))) void*)dst, 16, 0, 0);
#else
        uint4 v = *(const uint4*)src;
        *(uint4*)(dst + (size_t)lane * 8) = v;
#endif
    }
}

// ---------------------------------------------------------------------------
// GEMM body (R14-validated: global_load_lds staging + XOR swizzle).
// Y[m,n] = sum_k X[m,k]*W[n,k] + bias[n].
// ---------------------------------------------------------------------------
__device__ __forceinline__ void gemm_body(const bf16* __restrict__ X, const bf16* __restrict__ W,
                                          const bf16* __restrict__ bias, void* __restrict__ Yv,
                                          const int* __restrict__ flagp, int flex_out, int vt_out,
                                          unsigned short* smem, int m0, int n0)
{
    unsigned short* xs = smem;             // [64][256] linear, swizzled blocks
    unsigned short* ws = smem + 64 * 256;  // [64][256] linear, swizzled blocks
    const int t = threadIdx.x;
    const int w = t >> 6, lane = t & 63;

    stage_ws4(X + (size_t)m0 * DD, xs, w, lane);
    stage_ws4(W + (size_t)n0 * DD, ws, w, lane);
    __syncthreads();

    const int lrow = lane & 15, quad = lane >> 4, rgrp = quad * 4;
    floatx4 acc[4] = {};
    #pragma unroll
    for (int kt = 0; kt < 8; ++kt) {
        int kb = ((kt * 4 + quad) ^ (lrow & 7)) << 3;
        short8 a = *(const short8*)&xs[(w * 16 + lrow) * DD + kb];
        #pragma unroll
        for (int j = 0; j < 4; ++j) {
            short8 b = *(const short8*)&ws[(j * 16 + lrow) * DD + kb];
            acc[j] = __builtin_amdgcn_mfma_f32_16x16x32_bf16(a, b, acc[j], 0, 0, 0);
        }
    }

    if (vt_out) {
        __syncthreads();
        unsigned short* ts = xs;
        #pragma unroll
        for (int j = 0; j < 4; ++j) {
            float bv = __bfloat162float(bias[n0 + j * 16 + lrow]);
            #pragma unroll
            for (int r = 0; r < 4; ++r)
                ts[(j * 16 + lrow) * 72 + w * 16 + rgrp + r] = f2bfbits(acc[j][r] + bv);
        }
        __syncthreads();
        const int bq = m0 >> 11, s0v = m0 & 2047, h = n0 >> 6;
        bf16* dstb = (bf16*)Yv + ((size_t)(bq * HH + h) * HD) * SS + s0v;
        for (int i = 0; i < 2; ++i) {
            int idx = t + i * 256, row = idx >> 3, ch = (idx & 7) * 8;
            *(uint4*)(dstb + (size_t)row * SS + ch) = *(const uint4*)&ts[row * 72 + ch];
        }
        return;
    }

    const bool f32o = flex_out && (*flagp != 0);
    #pragma unroll
    for (int j = 0; j < 4; ++j) {
        int col = n0 + j * 16 + lrow;
        float bv = __bfloat162float(bias[col]);
        #pragma unroll
        for (int r = 0; r < 4; ++r) {
            int row = m0 + w * 16 + rgrp + r;
            float val = acc[j][r] + bv;
            if (f32o) ((float*)Yv)[(size_t)row * DD + col] = val;
            else      ((bf16*)Yv)[(size_t)row * DD + col] = __float2bfloat16(val);
        }
    }
}

#define WS_HALF (64 * 256)           // ushorts per ws buffer half
#define CONDS_OFF 65536              // bytes: after ws[2][64*256]
#define KBST_OFF  75776              // bytes: after conds[128*40]
#define SMEM_BYTES 80896
#define CT 132                        // condsT stride (8B-aligned per class row)

// ---------------------------------------------------------------------------
// Class-dependent key — R15: R7 structure with the conds LDS-port diet.
// Counters showed the LDS port ~86% busy; 33% of its traffic was 16 scalar
// ds_read_b32 conds reads per wave per class. Now conds is staged TRANSPOSED
// (condsT[c][row], stride 132) so each wave reads 4 x ds_read_b64 broadcast
// reads per class instead (4 quads -> 4 distinct banks, free broadcast).
// Row-major conds[128][40] + kbsT[64][40] are staged AFTER the class loop
// (overlaying the dead condsT) for the unchanged bias-MFMA + reduction.
// ---------------------------------------------------------------------------
__device__ __forceinline__ void classkey_body(const bf16* __restrict__ X, const bf16* __restrict__ Cond,
                                              const bf16* __restrict__ Wk, const bf16* __restrict__ Wkb,
                                              bf16* __restrict__ Kout,
                                              unsigned char* smem, int m0, int n0)
{
    unsigned short* wsbase = (unsigned short*)smem;                 // [2][64*256]
    unsigned short* condsT = (unsigned short*)(smem + CONDS_OFF);   // [32][CT] (class loop)

    const int t    = threadIdx.x;
    const int w    = t >> 6;
    const int lane = t & 63;
    const int r16  = lane & 15;
    const int quad = lane >> 4;
    const int mw   = w & 1;          // row half (0: rows 0-63, 1: rows 64-127)
    const int kw   = w >> 1;         // K half   (0: k 0-127,  1: k 128-255)

    // stage condsT[c][row] = Cond[m0+row][c]  (transposed; b16 scatter, once)
    {
        int row = t >> 1, cbase = (t & 1) * 16;
        uint4 a = *(const uint4*)(Cond + (size_t)(m0 + row) * CC + cbase);
        uint4 b = *(const uint4*)(Cond + (size_t)(m0 + row) * CC + cbase + 8);
        const unsigned short* va = (const unsigned short*)&a;
        const unsigned short* vb = (const unsigned short*)&b;
        #pragma unroll
        for (int e = 0; e < 8; ++e)
            condsT[(cbase + e) * CT + row] = va[e];
        #pragma unroll
        for (int e = 0; e < 8; ++e)
            condsT[(cbase + 8 + e) * CT + row] = vb[e];
    }

    // X fragments: 64 rows (mw half) x 128 K (kw half) per wave, in registers
    short8 xa[4][4];
    #pragma unroll
    for (int mt = 0; mt < 4; ++mt) {
        const bf16* xrow = X + (size_t)(m0 + mw * 64 + mt * 16 + r16) * DD + kw * 128 + quad * 8;
        #pragma unroll
        for (int kt = 0; kt < 4; ++kt)
            xa[mt][kt] = *(const short8*)(xrow + kt * 32);
    }

    stage_ws4(Wk + (size_t)n0 * DD, wsbase, w, lane);

    floatx4 acck[4][4] = {};
    for (int c = 0; c < CC; ++c) {
        __syncthreads();
        if (c + 1 < CC)
            stage_ws4(Wk + (size_t)(c + 1) * DD * DD + (size_t)n0 * DD,
                      wsbase + ((c + 1) & 1) * WS_HALF, w, lane);

        const unsigned short* wb = wsbase + (c & 1) * WS_HALF;
        floatx4 p[4][4];
        #pragma unroll
        for (int kt = 0; kt < 4; ++kt) {
            short8 bj[4];
            #pragma unroll
            for (int j = 0; j < 4; ++j)
                bj[j] = *(const short8*)&wb[(j * 16 + r16) * DD +
                          (((kw * 16 + kt * 4 + quad) ^ (r16 & 7)) << 3)];
            if (kt == 0) {
                floatx4 z = {};
                #pragma unroll
                for (int mt = 0; mt < 4; ++mt)
                    #pragma unroll
                    for (int j = 0; j < 4; ++j)
                        p[mt][j] = __builtin_amdgcn_mfma_f32_16x16x32_bf16(xa[mt][0], bj[j], z, 0, 0, 0);
            } else {
                #pragma unroll
                for (int mt = 0; mt < 4; ++mt)
                    #pragma unroll
                    for (int j = 0; j < 4; ++j)
                        p[mt][j] = __builtin_amdgcn_mfma_f32_16x16x32_bf16(xa[mt][kt], bj[j], p[mt][j], 0, 0, 0);
            }
        }
        #pragma unroll
        for (int mt = 0; mt < 4; ++mt) {
            // one b64 broadcast read delivers cv for r=0..3 (was 4x b32)
            short4v cvp = *(const short4v*)&condsT[c * CT + mw * 64 + mt * 16 + quad * 4];
            #pragma unroll
            for (int r = 0; r < 4; ++r) {
                float cv = bf2f((unsigned short)cvp[r]);
                #pragma unroll
                for (int j = 0; j < 4; ++j) acck[mt][j][r] += cv * p[mt][j][r];
            }
        }
    }

    // ---- end phase: restage row-major conds + kbsT over dead condsT ----
    unsigned short* conds = (unsigned short*)(smem + CONDS_OFF);   // [128][40]
    unsigned short* kbsT  = (unsigned short*)(smem + KBST_OFF);    // [64][40]
    __syncthreads();   // all waves done with condsT + last ws tile
    {
        int row = t >> 1, c16 = (t & 1) * 16;
        *(uint4*)&conds[row * 40 + c16]     = *(const uint4*)(Cond + (size_t)(m0 + row) * CC + c16);
        *(uint4*)&conds[row * 40 + c16 + 8] = *(const uint4*)(Cond + (size_t)(m0 + row) * CC + c16 + 8);
    }
    {
        int f = t >> 2, cbase = (t & 3) * 8;
        #pragma unroll
        for (int e = 0; e < 8; ++e)
            kbsT[f * 40 + cbase + e] =
                __builtin_bit_cast(unsigned short, Wkb[(size_t)(cbase + e) * DD + n0 + f]);
    }
    __syncthreads();

    // bias: acck += cond(128x32) @ WkbT(32x64) — one K=32 MFMA per (mt,j).
    // Only kw==0 waves add it (covers all 128 rows via mw).
    if (kw == 0) {
        #pragma unroll
        for (int mt = 0; mt < 4; ++mt) {
            short8 ac = *(const short8*)&conds[(mw * 64 + mt * 16 + r16) * 40 + quad * 8];
            #pragma unroll
            for (int j = 0; j < 4; ++j) {
                short8 bc = *(const short8*)&kbsT[(j * 16 + r16) * 40 + quad * 8];
                acck[mt][j] = __builtin_amdgcn_mfma_f32_16x16x32_bf16(ac, bc, acck[mt][j], 0, 0, 0);
            }
        }
    }

    // cross-K reduction via LDS fp32 [2][128][65] (66560 B, overlays ws+conds)
    float* red = (float*)smem;
    __syncthreads();
    #pragma unroll
    for (int mt = 0; mt < 4; ++mt)
        #pragma unroll
        for (int j = 0; j < 4; ++j)
            #pragma unroll
            for (int r = 0; r < 4; ++r)
                red[(kw * 128 + mw * 64 + mt * 16 + quad * 4 + r) * 65 + j * 16 + r16] =
                    acck[mt][j][r];
    __syncthreads();
    {
        int row = t >> 1, cg = (t & 1) * 32;
        __align__(16) unsigned short outv[32];
        #pragma unroll
        for (int cc = 0; cc < 32; ++cc) {
            float s = red[(size_t)row * 65 + cg + cc] + red[(size_t)(128 + row) * 65 + cg + cc];
            outv[cc] = f2bfbits(s);
        }
        bf16* dst = Kout + (size_t)(m0 + row) * DD + n0 + cg;
        #pragma unroll
        for (int u = 0; u < 4; ++u)
            *(uint4*)(dst + u * 8) = *(const uint4*)&outv[u * 8];
    }
}

// ---------------------------------------------------------------------------
// Fused classkey + Q/V projection launch (R10-validated).
// ---------------------------------------------------------------------------
__launch_bounds__(256, 2)
__global__ void fused_ck_qv(const bf16* __restrict__ X, const bf16* __restrict__ Cond,
                            const bf16* __restrict__ Wk, const bf16* __restrict__ Wkb,
                            bf16* __restrict__ Kout,
                            const bf16* __restrict__ Wqw, const bf16* __restrict__ Wqb, bf16* __restrict__ Qout,
                            const bf16* __restrict__ Wvw, const bf16* __restrict__ Wvb, bf16* __restrict__ Vout,
                            const int* __restrict__ flagp)
{
    __shared__ __align__(16) unsigned char smem[SMEM_BYTES];
    int id = blockIdx.x;
    if (id < 512) {
        int n0 = (id & 3) * 64, m0 = (id >> 2) * 128;
        classkey_body(X, Cond, Wk, Wkb, Kout, smem, m0, n0);
    } else {
        int gi = id - 512;
        if (gi < 1024) {
            int n0 = (gi & 3) * 64, m0 = (gi >> 2) * 64;
            gemm_body(X, Wqw, Wqb, (void*)Qout, flagp, 0, 0, (unsigned short*)smem, m0, n0);
        } else {
            gi -= 1024;
            int n0 = (gi & 3) * 64, m0 = (gi >> 2) * 64;
            gemm_body(X, Wvw, Wvb, (void*)Vout, flagp, 0, 1, (unsigned short*)smem, m0, n0);
        }
    }
}

// standalone gemm for the output projection
__launch_bounds__(256, 2)
__global__ void gemm_bias(const bf16* __restrict__ X, const bf16* __restrict__ W,
                          const bf16* __restrict__ bias, void* __restrict__ Yv,
                          const int* __restrict__ flagp, int flex_out, int vt_out)
{
    __shared__ __align__(16) unsigned short smem[2 * 64 * 256];
    gemm_body(X, W, bias, Yv, flagp, flex_out, vt_out, smem, blockIdx.y * 64, blockIdx.x * 64);
}

// ---------------------------------------------------------------------------
// Flash attention v3 (R8/R10-validated, exact).
// ---------------------------------------------------------------------------
__device__ inline void stage_kv(const bf16* __restrict__ kRow,
                                const bf16* __restrict__ vRow,
                                unsigned short* kbuf, unsigned short* vbuf,
                                int w, int lane)
{
    int r  = w * 8 + (lane >> 3);
    int cs = (lane & 7) ^ (r & 7);
#if HAVE_GLL
    __builtin_amdgcn_global_load_lds(
        (const __attribute__((address_space(1))) void*)(kRow + (size_t)r * DD + cs * 8),
        (__attribute__((address_space(3))) void*)(kbuf + w * 512), 16, 0, 0);
    __builtin_amdgcn_global_load_lds(
        (const __attribute__((address_space(1))) void*)(vRow + (size_t)r * SS + cs * 8),
        (__attribute__((address_space(3))) void*)(vbuf + w * 512), 16, 0, 0);
#else
    *(uint4*)(kbuf + w * 512 + (size_t)lane * 8) = *(const uint4*)(kRow + (size_t)r * DD + cs * 8);
    *(uint4*)(vbuf + w * 512 + (size_t)lane * 8) = *(const uint4*)(vRow + (size_t)r * SS + cs * 8);
#endif
}

__launch_bounds__(512, 4)
__global__ void attn(const bf16* __restrict__ Q, const bf16* __restrict__ Kb,
                     const bf16* __restrict__ VT, bf16* __restrict__ O)
{
    __shared__ __align__(16) unsigned short ks[2][64 * 64];
    __shared__ __align__(16) unsigned short vt[2][64 * 64];
#if !HAVE_PV16
    __shared__ __align__(16) unsigned short ps[128 * 72];
#endif
    const int t    = threadIdx.x;
    const int w    = t >> 6;
    const int lane = t & 63;
    const int r16  = lane & 15;
    const int quad = lane >> 4;
    const int bh   = blockIdx.y;
    const int b    = bh >> 2, h = bh & 3;
    const int q0   = blockIdx.x * 128;
    const size_t base  = ((size_t)b * SS) * DD + h * HD;
    const size_t vbase = (size_t)bh * HD * SS;

    // Q pre-scaled by 1/sqrt(HD) * log2(e) -> scores in log2 domain
    const float QSC = 0.125f * 1.4426950408889634f;
    short8 qa[2];
    {
        const bf16* qrow = Q + base + (size_t)(q0 + w * 16 + r16) * DD + quad * 8;
        #pragma unroll
        for (int k2 = 0; k2 < 2; ++k2) {
            short8 raw = *(const short8*)(qrow + k2 * 32);
            short8 sc;
            #pragma unroll
            for (int e = 0; e < 8; ++e)
                sc[e] = (short)f2bfbits(bf2f((unsigned short)raw[e]) * QSC);
            qa[k2] = sc;
        }
    }

    stage_kv(Kb + base, VT + vbase, &ks[0][0], &vt[0][0], w, lane);

    floatx4 acco[4] = {};
    floatx4 accl = {};           // softmax denominator via ones-MFMA
    float mrun = -1e30f;

#if HAVE_PV16
    const short4v ones4 = { (short)0x3F80, (short)0x3F80, (short)0x3F80, (short)0x3F80 };
#else
    short8 ones8;
    #pragma unroll
    for (int e = 0; e < 8; ++e) ones8[e] = (short)0x3F80;
#endif

    for (int kt = 0; kt < SS / 64; ++kt) {
        __syncthreads();
        if (kt + 1 < SS / 64)
            stage_kv(Kb + base + (size_t)(kt + 1) * 64 * DD,
                     VT + vbase + (size_t)(kt + 1) * 64,
                     &ks[(kt + 1) & 1][0], &vt[(kt + 1) & 1][0], w, lane);

        const unsigned short* kbuf = &ks[kt & 1][0];
        const unsigned short* vbuf = &vt[kt & 1][0];

        floatx4 s[4] = {};
        #pragma unroll
        for (int k2 = 0; k2 < 2; ++k2) {
            short8 bq = qa[k2];
            #pragma unroll
            for (int j = 0; j < 4; ++j) {
                short8 ak = *(const short8*)&kbuf[(j * 16 + r16) * 64 +
                                                  (((k2 * 4 + quad) ^ (r16 & 7)) << 3)];
                s[j] = __builtin_amdgcn_mfma_f32_16x16x32_bf16(ak, bq, s[j], 0, 0, 0);
            }
        }

        // row max: max3 tree over 16 values, then cross-quad combine
        float g0 = max3f(s[0][0], s[0][1], s[0][2]);
        float g1 = max3f(s[0][3], s[1][0], s[1][1]);
        float g2 = max3f(s[1][2], s[1][3], s[2][0]);
        float g3 = max3f(s[2][1], s[2][2], s[2][3]);
        float g4 = max3f(s[3][0], s[3][1], s[3][2]);
        float mx = fmaxf(max3f(g0, g1, g2), max3f(g3, g4, s[3][3]));
        mx = fmaxf(mx, __shfl_xor(mx, 16, 64));
        mx = fmaxf(mx, __shfl_xor(mx, 32, 64));

        // defer-max: only rescale when max grew past THR=8 (log2 units)
        if (__any(mx > mrun + 8.0f)) {
            float mnew  = fmaxf(mrun, mx);
            float alpha = EXP2F(mrun - mnew);
            mrun = mnew;
            #pragma unroll
            for (int r = 0; r < 4; ++r) {
                float ar = __shfl(alpha, (quad << 4) + quad * 4 + r, 64);
                #pragma unroll
                for (int jn = 0; jn < 4; ++jn) acco[jn][r] *= ar;
                accl[r] *= ar;
            }
        }

        #pragma unroll
        for (int j = 0; j < 4; ++j)
            #pragma unroll
            for (int r = 0; r < 4; ++r)
                s[j][r] = EXP2F(s[j][r] - mrun);

#if HAVE_PV16
        #pragma unroll
        for (int j = 0; j < 4; ++j) {
            short4v p;
            p[0] = (short)f2bfbits(s[j][0]); p[1] = (short)f2bfbits(s[j][1]);
            p[2] = (short)f2bfbits(s[j][2]); p[3] = (short)f2bfbits(s[j][3]);
            accl = MFMA_PV16(p, ones4, accl);
            #pragma unroll
            for (int jn = 0; jn < 4; ++jn) {
                short4v vv = *(const short4v*)&vbuf[(jn * 16 + r16) * 64 +
                                                    ((((j * 2) + (quad >> 1)) ^ (r16 & 7)) << 3) +
                                                    (quad & 1) * 4];
                acco[jn] = MFMA_PV16(p, vv, acco[jn]);
            }
        }
#else
        #pragma unroll
        for (int j = 0; j < 4; ++j)
            #pragma unroll
            for (int r = 0; r < 4; ++r)
                ps[(w * 16 + r16) * 72 + j * 16 + quad * 4 + r] = f2bfbits(s[j][r]);
        #pragma unroll
        for (int k2 = 0; k2 < 2; ++k2) {
            short8 a = *(const short8*)&ps[(w * 16 + r16) * 72 + k2 * 32 + quad * 8];
            accl = __builtin_amdgcn_mfma_f32_16x16x32_bf16(a, ones8, accl, 0, 0, 0);
            #pragma unroll
            for (int jn = 0; jn < 4; ++jn) {
                short8 bb = *(const short8*)&vbuf[(jn * 16 + r16) * 64 +
                                                  (((k2 * 4 + quad) ^ (r16 & 7)) << 3)];
                acco[jn] = __builtin_amdgcn_mfma_f32_16x16x32_bf16(a, bb, acco[jn], 0, 0, 0);
            }
        }
#endif
    }

    // accl rows match acco rows (all 16 cols equal) -> no shfl needed
    #pragma unroll
    for (int r = 0; r < 4; ++r) {
        float inv = 1.0f / accl[r];
        int row = q0 + w * 16 + quad * 4 + r;
        #pragma unroll
        for (int jn = 0; jn < 4; ++jn)
            O[base + (size_t)row * DD + jn * 16 + r16] = __float2bfloat16(acco[jn][r] * inv);
    }
}

// ---------------------------------------------------------------------------
extern "C" void kernel_launch(void* const* d_in, const int* in_sizes, int n_in,
                              void* d_out, int out_size, void* d_ws, size_t ws_size,
                              hipStream_t stream)
{
    int*  flag = (int*)d_ws;
    bf16* conv = (bf16*)((char*)d_ws + 256);

    const bf16* xb    = conv + P0;
    const bf16* condb = conv + P1;
    const bf16* wqw   = conv + P2;
    const bf16* wqb   = conv + P3;
    const bf16* wvw   = conv + P4;
    const bf16* wvb   = conv + P5;
    const bf16* wkw   = conv + P6;
    const bf16* wkb   = conv + P7;
    const bf16* wow   = conv + P8;
    const bf16* wob   = conv + P9;

    bf16* qb = conv + PTOT;
    bf16* kb = qb + (size_t)MTOT * DD;
    bf16* vb = kb + (size_t)MTOT * DD;   // V^T layout [b*H+h][hd][S]
    bf16* ob = vb + (size_t)MTOT * DD;

    dim3 blk(256);
    hipLaunchKernelGGL(convert_all, dim3((PTOT / 8 + 255) / 256), blk, 0, stream,
                       d_in[0], d_in[1], d_in[2], d_in[3], d_in[4],
                       d_in[5], d_in[6], d_in[7], d_in[8], d_in[9],
                       conv, flag);

    // fused: 512 classkey blocks (first) + 2048 gemm_qv blocks
    hipLaunchKernelGGL(fused_ck_qv, dim3(512 + 2048), blk, 0, stream,
                       xb, condb, wkw, wkb, kb,
                       wqw, wqb, qb, wvw, wvb, vb, flag);

    dim3 ga(SS / 128, BB * HH);          // (16, 32), 512-thread blocks
    hipLaunchKernelGGL(attn, ga, dim3(512), 0, stream, qb, kb, vb, ob);

    dim3 gg(DD / 64, MTOT / 64);
    hipLaunchKernelGGL(gemm_bias, gg, blk, 0, stream, ob, wow, wob, d_out, flag, 1, 0);
}

// Round 11
// 229.006 us; speedup vs baseline: 1.0316x; 1.0316x over previous
//
#include <hip/hip_runtime.h>
#include <hip/hip_bf16.h>

#define BB 8
#define SS 2048
#define DD 256
#define CC 32
#define HH 4
#define HD 64
#define MTOT (BB*SS)   // 16384 tokens

using bf16    = __hip_bfloat16;
using short8  = __attribute__((ext_vector_type(8))) short;
using short4v = __attribute__((ext_vector_type(4))) short;
using floatx4 = __attribute__((ext_vector_type(4))) float;

#if __has_builtin(__builtin_amdgcn_mfma_f32_16x16x16_bf16)
  #define MFMA_PV16(a,b,c) __builtin_amdgcn_mfma_f32_16x16x16_bf16(a,b,c,0,0,0)
  #define HAVE_PV16 1
#elif __has_builtin(__builtin_amdgcn_mfma_f32_16x16x16bf16_1k)
  #define MFMA_PV16(a,b,c) __builtin_amdgcn_mfma_f32_16x16x16bf16_1k(a,b,c,0,0,0)
  #define HAVE_PV16 1
#else
  #define HAVE_PV16 0
#endif

#if __has_builtin(__builtin_amdgcn_global_load_lds)
  #define HAVE_GLL 1
#else
  #define HAVE_GLL 0
#endif

#if __has_builtin(__builtin_amdgcn_exp2f)
  #define EXP2F(x) __builtin_amdgcn_exp2f(x)
#else
  #define EXP2F(x) exp2f(x)
#endif

__device__ inline float bf2f(unsigned short u) {
    union { unsigned int i; float f; } v; v.i = ((unsigned int)u) << 16; return v.f;
}
__device__ inline unsigned short f2bfbits(float f) {
    bf16 h = __float2bfloat16(f);
    return __builtin_bit_cast(unsigned short, h);
}
// 3-input max; clang fuses nested fmaxf to v_max3_f32 on gfx9+
__device__ inline float max3f(float a, float b, float c) {
    return fmaxf(fmaxf(a, b), c);
}

// --------------------------------------------------------------------------
#define N_X    (MTOT*DD)
#define N_COND (MTOT*CC)
#define N_WQW  (DD*DD)
#define N_WQB  (DD)
#define N_WVW  (DD*DD)
#define N_WVB  (DD)
#define N_WKW  (CC*DD*DD)
#define N_WKB  (CC*DD)
#define N_WOW  (DD*DD)
#define N_WOB  (DD)
#define P0 0
#define P1 (P0+N_X)
#define P2 (P1+N_COND)
#define P3 (P2+N_WQW)
#define P4 (P3+N_WQB)
#define P5 (P4+N_WVW)
#define P6 (P5+N_WVB)
#define P7 (P6+N_WKW)
#define P8 (P7+N_WKB)
#define P9 (P8+N_WOW)
#define PTOT (P9+N_WOB)

// --------------------------------------------------------------------------
// Fused dtype-detect + conversion. Each block self-detects from 256 sampled
// words of x (fp32 N(0,1): ~all in [1e-4,1e4]; bf16-pair-garbage: ~none).
// Block 0 publishes the flag for the final GEMM's epilogue.
// --------------------------------------------------------------------------
__global__ void convert_all(const void* s0, const void* s1, const void* s2,
                            const void* s3, const void* s4, const void* s5,
                            const void* s6, const void* s7, const void* s8,
                            const void* s9, bf16* dst, int* flagw)
{
    __shared__ int cnts[4];
    {
        const float* xf = (const float*)s0;
        float v = fabsf(xf[threadIdx.x]);
        bool ok = (v == v) && v > 1e-4f && v < 1e4f;
        unsigned long long m = __ballot(ok);
        if ((threadIdx.x & 63) == 0) cnts[threadIdx.x >> 6] = __popcll(m);
    }
    __syncthreads();
    const bool f32 = (cnts[0] + cnts[1] + cnts[2] + cnts[3]) > 128;
    if (blockIdx.x == 0 && threadIdx.x == 0) *flagw = f32 ? 1 : 0;

    size_t i = ((size_t)blockIdx.x * 256 + threadIdx.x) * 8;
    const size_t stride = (size_t)gridDim.x * 256 * 8;
    for (; i < (size_t)PTOT; i += stride) {
        const void* src; size_t off;
        if      (i < P1) { src = s0; off = i - P0; }
        else if (i < P2) { src = s1; off = i - P1; }
        else if (i < P3) { src = s2; off = i - P2; }
        else if (i < P4) { src = s3; off = i - P3; }
        else if (i < P5) { src = s4; off = i - P4; }
        else if (i < P6) { src = s5; off = i - P5; }
        else if (i < P7) { src = s6; off = i - P6; }
        else if (i < P8) { src = s7; off = i - P7; }
        else if (i < P9) { src = s8; off = i - P8; }
        else             { src = s9; off = i - P9; }
        if (f32) {
            const float* s = (const float*)src + off;
            float4 a = *(const float4*)(s);
            float4 b = *(const float4*)(s + 4);
            __align__(16) unsigned short t[8];
            t[0] = f2bfbits(a.x); t[1] = f2bfbits(a.y);
            t[2] = f2bfbits(a.z); t[3] = f2bfbits(a.w);
            t[4] = f2bfbits(b.x); t[5] = f2bfbits(b.y);
            t[6] = f2bfbits(b.z); t[7] = f2bfbits(b.w);
            *(uint4*)(dst + i) = *(const uint4*)t;
        } else {
            *(uint4*)(dst + i) = *(const uint4*)((const unsigned short*)src + off);
        }
    }
}

// ---------------------------------------------------------------------------
// Shared staging helper (classkey-validated): stages a 64-row x 256-col bf16
// tile into linear LDS via width-16 global_load_lds, with XOR chunk swizzle
// on the GLOBAL source (rule #21: linear dst + inv-swizzled src + swizzled
// read). LDS[row][b] = global[row][b ^ (row&7)] in 8-element blocks.
// ---------------------------------------------------------------------------
__device__ __forceinline__ void stage_ws4(const bf16* __restrict__ Wc,
                                          unsigned short* wsbuf, int w, int lane)
{
    #pragma unroll
    for (int i = 0; i < 8; ++i) {
        int rr = w * 16 + i * 2 + (lane >> 5);
        int cs = (lane & 31) ^ (rr & 7);
        const bf16* src = Wc + (size_t)rr * DD + cs * 8;
        unsigned short* dst = wsbuf + (size_t)(w * 16 + i * 2) * DD;
#if HAVE_GLL
        __builtin_amdgcn_global_load_lds(
            (const __attribute__((address_space(1))) void*)src,
            (__attribute__((address_space(3))) void*)dst, 16, 0, 0);
#else
        uint4 v = *(const uint4*)src;
        *(uint4*)(dst + (size_t)lane * 8) = v;
#endif
    }
}

// ---------------------------------------------------------------------------
// GEMM body (R14-validated: global_load_lds staging + XOR swizzle).
// Y[m,n] = sum_k X[m,k]*W[n,k] + bias[n].
// ---------------------------------------------------------------------------
__device__ __forceinline__ void gemm_body(const bf16* __restrict__ X, const bf16* __restrict__ W,
                                          const bf16* __restrict__ bias, void* __restrict__ Yv,
                                          const int* __restrict__ flagp, int flex_out, int vt_out,
                                          unsigned short* smem, int m0, int n0)
{
    unsigned short* xs = smem;             // [64][256] linear, swizzled blocks
    unsigned short* ws = smem + 64 * 256;  // [64][256] linear, swizzled blocks
    const int t = threadIdx.x;
    const int w = t >> 6, lane = t & 63;

    stage_ws4(X + (size_t)m0 * DD, xs, w, lane);
    stage_ws4(W + (size_t)n0 * DD, ws, w, lane);
    __syncthreads();

    const int lrow = lane & 15, quad = lane >> 4, rgrp = quad * 4;
    floatx4 acc[4] = {};
    #pragma unroll
    for (int kt = 0; kt < 8; ++kt) {
        int kb = ((kt * 4 + quad) ^ (lrow & 7)) << 3;
        short8 a = *(const short8*)&xs[(w * 16 + lrow) * DD + kb];
        #pragma unroll
        for (int j = 0; j < 4; ++j) {
            short8 b = *(const short8*)&ws[(j * 16 + lrow) * DD + kb];
            acc[j] = __builtin_amdgcn_mfma_f32_16x16x32_bf16(a, b, acc[j], 0, 0, 0);
        }
    }

    if (vt_out) {
        __syncthreads();
        unsigned short* ts = xs;
        #pragma unroll
        for (int j = 0; j < 4; ++j) {
            float bv = __bfloat162float(bias[n0 + j * 16 + lrow]);
            #pragma unroll
            for (int r = 0; r < 4; ++r)
                ts[(j * 16 + lrow) * 72 + w * 16 + rgrp + r] = f2bfbits(acc[j][r] + bv);
        }
        __syncthreads();
        const int bq = m0 >> 11, s0v = m0 & 2047, h = n0 >> 6;
        bf16* dstb = (bf16*)Yv + ((size_t)(bq * HH + h) * HD) * SS + s0v;
        for (int i = 0; i < 2; ++i) {
            int idx = t + i * 256, row = idx >> 3, ch = (idx & 7) * 8;
            *(uint4*)(dstb + (size_t)row * SS + ch) = *(const uint4*)&ts[row * 72 + ch];
        }
        return;
    }

    const bool f32o = flex_out && (*flagp != 0);
    #pragma unroll
    for (int j = 0; j < 4; ++j) {
        int col = n0 + j * 16 + lrow;
        float bv = __bfloat162float(bias[col]);
        #pragma unroll
        for (int r = 0; r < 4; ++r) {
            int row = m0 + w * 16 + rgrp + r;
            float val = acc[j][r] + bv;
            if (f32o) ((float*)Yv)[(size_t)row * DD + col] = val;
            else      ((bf16*)Yv)[(size_t)row * DD + col] = __float2bfloat16(val);
        }
    }
}

#define WS_HALF (64 * 256)           // ushorts per ws buffer half
#define CONDS_OFF 65536              // bytes: after ws[2][64*256]
#define KBST_OFF  75776              // bytes: after conds[128*40]
#define SMEM_BYTES 80896

// ---------------------------------------------------------------------------
// Class-dependent key — R7-validated body (71 us): K-split waves, conds
// stride 40 (reads are 16-lane broadcasts — R15's "diet" of these reads
// REGRESSED 11%, do not touch), bias via K=32 MFMA, cross-K fp32 LDS reduce.
// ---------------------------------------------------------------------------
__device__ __forceinline__ void classkey_body(const bf16* __restrict__ X, const bf16* __restrict__ Cond,
                                              const bf16* __restrict__ Wk, const bf16* __restrict__ Wkb,
                                              bf16* __restrict__ Kout,
                                              unsigned char* smem, int m0, int n0)
{
    unsigned short* wsbase = (unsigned short*)smem;                 // [2][64*256]
    unsigned short* conds  = (unsigned short*)(smem + CONDS_OFF);   // [128][40]
    unsigned short* kbsT   = (unsigned short*)(smem + KBST_OFF);    // [64][40]

    const int t    = threadIdx.x;
    const int w    = t >> 6;
    const int lane = t & 63;
    const int r16  = lane & 15;
    const int quad = lane >> 4;
    const int mw   = w & 1;          // row half (0: rows 0-63, 1: rows 64-127)
    const int kw   = w >> 1;         // K half   (0: k 0-127,  1: k 128-255)

    // stage conds [128][40] (stride 40 = 20 dwords -> quad rows on distinct banks)
    {
        int row = t >> 1, c16 = (t & 1) * 16;
        *(uint4*)&conds[row * 40 + c16]     = *(const uint4*)(Cond + (size_t)(m0 + row) * CC + c16);
        *(uint4*)&conds[row * 40 + c16 + 8] = *(const uint4*)(Cond + (size_t)(m0 + row) * CC + c16 + 8);
    }
    // stage kbsT[f][c] = Wkb[c][n0+f]  (transposed so bias can go through MFMA)
    {
        int f = t >> 2, cbase = (t & 3) * 8;
        #pragma unroll
        for (int e = 0; e < 8; ++e)
            kbsT[f * 40 + cbase + e] =
                __builtin_bit_cast(unsigned short, Wkb[(size_t)(cbase + e) * DD + n0 + f]);
    }

    // X fragments: 64 rows (mw half) x 128 K (kw half) per wave, in registers
    short8 xa[4][4];
    #pragma unroll
    for (int mt = 0; mt < 4; ++mt) {
        const bf16* xrow = X + (size_t)(m0 + mw * 64 + mt * 16 + r16) * DD + kw * 128 + quad * 8;
        #pragma unroll
        for (int kt = 0; kt < 4; ++kt)
            xa[mt][kt] = *(const short8*)(xrow + kt * 32);
    }

    stage_ws4(Wk + (size_t)n0 * DD, wsbase, w, lane);

    floatx4 acck[4][4] = {};
    for (int c = 0; c < CC; ++c) {
        __syncthreads();
        if (c + 1 < CC)
            stage_ws4(Wk + (size_t)(c + 1) * DD * DD + (size_t)n0 * DD,
                      wsbase + ((c + 1) & 1) * WS_HALF, w, lane);

        const unsigned short* wb = wsbase + (c & 1) * WS_HALF;
        floatx4 p[4][4];
        #pragma unroll
        for (int kt = 0; kt < 4; ++kt) {
            short8 bj[4];
            #pragma unroll
            for (int j = 0; j < 4; ++j)
                bj[j] = *(const short8*)&wb[(j * 16 + r16) * DD +
                          (((kw * 16 + kt * 4 + quad) ^ (r16 & 7)) << 3)];
            if (kt == 0) {
                floatx4 z = {};
                #pragma unroll
                for (int mt = 0; mt < 4; ++mt)
                    #pragma unroll
                    for (int j = 0; j < 4; ++j)
                        p[mt][j] = __builtin_amdgcn_mfma_f32_16x16x32_bf16(xa[mt][0], bj[j], z, 0, 0, 0);
            } else {
                #pragma unroll
                for (int mt = 0; mt < 4; ++mt)
                    #pragma unroll
                    for (int j = 0; j < 4; ++j)
                        p[mt][j] = __builtin_amdgcn_mfma_f32_16x16x32_bf16(xa[mt][kt], bj[j], p[mt][j], 0, 0, 0);
            }
        }
        #pragma unroll
        for (int mt = 0; mt < 4; ++mt)
            #pragma unroll
            for (int r = 0; r < 4; ++r) {
                float cv = bf2f(conds[(mw * 64 + mt * 16 + quad * 4 + r) * 40 + c]);
                #pragma unroll
                for (int j = 0; j < 4; ++j) acck[mt][j][r] += cv * p[mt][j][r];
            }
    }

    // bias: acck += cond(128x32) @ WkbT(32x64) — one K=32 MFMA per (mt,j).
    // Only kw==0 waves add it (covers all 128 rows via mw).
    if (kw == 0) {
        #pragma unroll
        for (int mt = 0; mt < 4; ++mt) {
            short8 ac = *(const short8*)&conds[(mw * 64 + mt * 16 + r16) * 40 + quad * 8];
            #pragma unroll
            for (int j = 0; j < 4; ++j) {
                short8 bc = *(const short8*)&kbsT[(j * 16 + r16) * 40 + quad * 8];
                acck[mt][j] = __builtin_amdgcn_mfma_f32_16x16x32_bf16(ac, bc, acck[mt][j], 0, 0, 0);
            }
        }
    }

    // cross-K reduction via LDS fp32 [2][128][65] (66560 B, overlays ws+conds)
    float* red = (float*)smem;
    __syncthreads();
    #pragma unroll
    for (int mt = 0; mt < 4; ++mt)
        #pragma unroll
        for (int j = 0; j < 4; ++j)
            #pragma unroll
            for (int r = 0; r < 4; ++r)
                red[(kw * 128 + mw * 64 + mt * 16 + quad * 4 + r) * 65 + j * 16 + r16] =
                    acck[mt][j][r];
    __syncthreads();
    {
        int row = t >> 1, cg = (t & 1) * 32;
        __align__(16) unsigned short outv[32];
        #pragma unroll
        for (int cc = 0; cc < 32; ++cc) {
            float s = red[(size_t)row * 65 + cg + cc] + red[(size_t)(128 + row) * 65 + cg + cc];
            outv[cc] = f2bfbits(s);
        }
        bf16* dst = Kout + (size_t)(m0 + row) * DD + n0 + cg;
        #pragma unroll
        for (int u = 0; u < 4; ++u)
            *(uint4*)(dst + u * 8) = *(const uint4*)&outv[u * 8];
    }
}

// ---------------------------------------------------------------------------
// Fused classkey + Q/V projection launch (R10-validated).
// ---------------------------------------------------------------------------
__launch_bounds__(256, 2)
__global__ void fused_ck_qv(const bf16* __restrict__ X, const bf16* __restrict__ Cond,
                            const bf16* __restrict__ Wk, const bf16* __restrict__ Wkb,
                            bf16* __restrict__ Kout,
                            const bf16* __restrict__ Wqw, const bf16* __restrict__ Wqb, bf16* __restrict__ Qout,
                            const bf16* __restrict__ Wvw, const bf16* __restrict__ Wvb, bf16* __restrict__ Vout,
                            const int* __restrict__ flagp)
{
    __shared__ __align__(16) unsigned char smem[SMEM_BYTES];
    int id = blockIdx.x;
    if (id < 512) {
        int n0 = (id & 3) * 64, m0 = (id >> 2) * 128;
        classkey_body(X, Cond, Wk, Wkb, Kout, smem, m0, n0);
    } else {
        int gi = id - 512;
        if (gi < 1024) {
            int n0 = (gi & 3) * 64, m0 = (gi >> 2) * 64;
            gemm_body(X, Wqw, Wqb, (void*)Qout, flagp, 0, 0, (unsigned short*)smem, m0, n0);
        } else {
            gi -= 1024;
            int n0 = (gi & 3) * 64, m0 = (gi >> 2) * 64;
            gemm_body(X, Wvw, Wvb, (void*)Vout, flagp, 0, 1, (unsigned short*)smem, m0, n0);
        }
    }
}

// standalone gemm for the output projection
__launch_bounds__(256, 2)
__global__ void gemm_bias(const bf16* __restrict__ X, const bf16* __restrict__ W,
                          const bf16* __restrict__ bias, void* __restrict__ Yv,
                          const int* __restrict__ flagp, int flex_out, int vt_out)
{
    __shared__ __align__(16) unsigned short smem[2 * 64 * 256];
    gemm_body(X, W, bias, Yv, flagp, flex_out, vt_out, smem, blockIdx.y * 64, blockIdx.x * 64);
}

// ---------------------------------------------------------------------------
// Flash attention v3 (R8/R10-validated, exact).
// ---------------------------------------------------------------------------
__device__ inline void stage_kv(const bf16* __restrict__ kRow,
                                const bf16* __restrict__ vRow,
                                unsigned short* kbuf, unsigned short* vbuf,
                                int w, int lane)
{
    int r  = w * 8 + (lane >> 3);
    int cs = (lane & 7) ^ (r & 7);
#if HAVE_GLL
    __builtin_amdgcn_global_load_lds(
        (const __attribute__((address_space(1))) void*)(kRow + (size_t)r * DD + cs * 8),
        (__attribute__((address_space(3))) void*)(kbuf + w * 512), 16, 0, 0);
    __builtin_amdgcn_global_load_lds(
        (const __attribute__((address_space(1))) void*)(vRow + (size_t)r * SS + cs * 8),
        (__attribute__((address_space(3))) void*)(vbuf + w * 512), 16, 0, 0);
#else
    *(uint4*)(kbuf + w * 512 + (size_t)lane * 8) = *(const uint4*)(kRow + (size_t)r * DD + cs * 8);
    *(uint4*)(vbuf + w * 512 + (size_t)lane * 8) = *(const uint4*)(vRow + (size_t)r * SS + cs * 8);
#endif
}

__launch_bounds__(512, 4)
__global__ void attn(const bf16* __restrict__ Q, const bf16* __restrict__ Kb,
                     const bf16* __restrict__ VT, bf16* __restrict__ O)
{
    __shared__ __align__(16) unsigned short ks[2][64 * 64];
    __shared__ __align__(16) unsigned short vt[2][64 * 64];
#if !HAVE_PV16
    __shared__ __align__(16) unsigned short ps[128 * 72];
#endif
    const int t    = threadIdx.x;
    const int w    = t >> 6;
    const int lane = t & 63;
    const int r16  = lane & 15;
    const int quad = lane >> 4;
    const int bh   = blockIdx.y;
    const int b    = bh >> 2, h = bh & 3;
    const int q0   = blockIdx.x * 128;
    const size_t base  = ((size_t)b * SS) * DD + h * HD;
    const size_t vbase = (size_t)bh * HD * SS;

    // Q pre-scaled by 1/sqrt(HD) * log2(e) -> scores in log2 domain
    const float QSC = 0.125f * 1.4426950408889634f;
    short8 qa[2];
    {
        const bf16* qrow = Q + base + (size_t)(q0 + w * 16 + r16) * DD + quad * 8;
        #pragma unroll
        for (int k2 = 0; k2 < 2; ++k2) {
            short8 raw = *(const short8*)(qrow + k2 * 32);
            short8 sc;
            #pragma unroll
            for (int e = 0; e < 8; ++e)
                sc[e] = (short)f2bfbits(bf2f((unsigned short)raw[e]) * QSC);
            qa[k2] = sc;
        }
    }

    stage_kv(Kb + base, VT + vbase, &ks[0][0], &vt[0][0], w, lane);

    floatx4 acco[4] = {};
    floatx4 accl = {};           // softmax denominator via ones-MFMA
    float mrun = -1e30f;

#if HAVE_PV16
    const short4v ones4 = { (short)0x3F80, (short)0x3F80, (short)0x3F80, (short)0x3F80 };
#else
    short8 ones8;
    #pragma unroll
    for (int e = 0; e < 8; ++e) ones8[e] = (short)0x3F80;
#endif

    for (int kt = 0; kt < SS / 64; ++kt) {
        __syncthreads();
        if (kt + 1 < SS / 64)
            stage_kv(Kb + base + (size_t)(kt + 1) * 64 * DD,
                     VT + vbase + (size_t)(kt + 1) * 64,
                     &ks[(kt + 1) & 1][0], &vt[(kt + 1) & 1][0], w, lane);

        const unsigned short* kbuf = &ks[kt & 1][0];
        const unsigned short* vbuf = &vt[kt & 1][0];

        floatx4 s[4] = {};
        #pragma unroll
        for (int k2 = 0; k2 < 2; ++k2) {
            short8 bq = qa[k2];
            #pragma unroll
            for (int j = 0; j < 4; ++j) {
                short8 ak = *(const short8*)&kbuf[(j * 16 + r16) * 64 +
                                                  (((k2 * 4 + quad) ^ (r16 & 7)) << 3)];
                s[j] = __builtin_amdgcn_mfma_f32_16x16x32_bf16(ak, bq, s[j], 0, 0, 0);
            }
        }

        // row max: max3 tree over 16 values, then cross-quad combine
        float g0 = max3f(s[0][0], s[0][1], s[0][2]);
        float g1 = max3f(s[0][3], s[1][0], s[1][1]);
        float g2 = max3f(s[1][2], s[1][3], s[2][0]);
        float g3 = max3f(s[2][1], s[2][2], s[2][3]);
        float g4 = max3f(s[3][0], s[3][1], s[3][2]);
        float mx = fmaxf(max3f(g0, g1, g2), max3f(g3, g4, s[3][3]));
        mx = fmaxf(mx, __shfl_xor(mx, 16, 64));
        mx = fmaxf(mx, __shfl_xor(mx, 32, 64));

        // defer-max: only rescale when max grew past THR=8 (log2 units)
        if (__any(mx > mrun + 8.0f)) {
            float mnew  = fmaxf(mrun, mx);
            float alpha = EXP2F(mrun - mnew);
            mrun = mnew;
            #pragma unroll
            for (int r = 0; r < 4; ++r) {
                float ar = __shfl(alpha, (quad << 4) + quad * 4 + r, 64);
                #pragma unroll
                for (int jn = 0; jn < 4; ++jn) acco[jn][r] *= ar;
                accl[r] *= ar;
            }
        }

        #pragma unroll
        for (int j = 0; j < 4; ++j)
            #pragma unroll
            for (int r = 0; r < 4; ++r)
                s[j][r] = EXP2F(s[j][r] - mrun);

#if HAVE_PV16
        #pragma unroll
        for (int j = 0; j < 4; ++j) {
            short4v p;
            p[0] = (short)f2bfbits(s[j][0]); p[1] = (short)f2bfbits(s[j][1]);
            p[2] = (short)f2bfbits(s[j][2]); p[3] = (short)f2bfbits(s[j][3]);
            accl = MFMA_PV16(p, ones4, accl);
            #pragma unroll
            for (int jn = 0; jn < 4; ++jn) {
                short4v vv = *(const short4v*)&vbuf[(jn * 16 + r16) * 64 +
                                                    ((((j * 2) + (quad >> 1)) ^ (r16 & 7)) << 3) +
                                                    (quad & 1) * 4];
                acco[jn] = MFMA_PV16(p, vv, acco[jn]);
            }
        }
#else
        #pragma unroll
        for (int j = 0; j < 4; ++j)
            #pragma unroll
            for (int r = 0; r < 4; ++r)
                ps[(w * 16 + r16) * 72 + j * 16 + quad * 4 + r] = f2bfbits(s[j][r]);
        #pragma unroll
        for (int k2 = 0; k2 < 2; ++k2) {
            short8 a = *(const short8*)&ps[(w * 16 + r16) * 72 + k2 * 32 + quad * 8];
            accl = __builtin_amdgcn_mfma_f32_16x16x32_bf16(a, ones8, accl, 0, 0, 0);
            #pragma unroll
            for (int jn = 0; jn < 4; ++jn) {
                short8 bb = *(const short8*)&vbuf[(jn * 16 + r16) * 64 +
                                                  (((k2 * 4 + quad) ^ (r16 & 7)) << 3)];
                acco[jn] = __builtin_amdgcn_mfma_f32_16x16x32_bf16(a, bb, acco[jn], 0, 0, 0);
            }
        }
#endif
    }

    // accl rows match acco rows (all 16 cols equal) -> no shfl needed
    #pragma unroll
    for (int r = 0; r < 4; ++r) {
        float inv = 1.0f / accl[r];
        int row = q0 + w * 16 + quad * 4 + r;
        #pragma unroll
        for (int jn = 0; jn < 4; ++jn)
            O[base + (size_t)row * DD + jn * 16 + r16] = __float2bfloat16(acco[jn][r] * inv);
    }
}

// ---------------------------------------------------------------------------
extern "C" void kernel_launch(void* const* d_in, const int* in_sizes, int n_in,
                              void* d_out, int out_size, void* d_ws, size_t ws_size,
                              hipStream_t stream)
{
    int*  flag = (int*)d_ws;
    bf16* conv = (bf16*)((char*)d_ws + 256);

    const bf16* xb    = conv + P0;
    const bf16* condb = conv + P1;
    const bf16* wqw   = conv + P2;
    const bf16* wqb   = conv + P3;
    const bf16* wvw   = conv + P4;
    const bf16* wvb   = conv + P5;
    const bf16* wkw   = conv + P6;
    const bf16* wkb   = conv + P7;
    const bf16* wow   = conv + P8;
    const bf16* wob   = conv + P9;

    bf16* qb = conv + PTOT;
    bf16* kb = qb + (size_t)MTOT * DD;
    bf16* vb = kb + (size_t)MTOT * DD;   // V^T layout [b*H+h][hd][S]
    bf16* ob = vb + (size_t)MTOT * DD;

    dim3 blk(256);
    hipLaunchKernelGGL(convert_all, dim3((PTOT / 8 + 255) / 256), blk, 0, stream,
                       d_in[0], d_in[1], d_in[2], d_in[3], d_in[4],
                       d_in[5], d_in[6], d_in[7], d_in[8], d_in[9],
                       conv, flag);

    // fused: 512 classkey blocks (first) + 2048 gemm_qv blocks
    hipLaunchKernelGGL(fused_ck_qv, dim3(512 + 2048), blk, 0, stream,
                       xb, condb, wkw, wkb, kb,
                       wqw, wqb, qb, wvw, wvb, vb, flag);

    dim3 ga(SS / 128, BB * HH);          // (16, 32), 512-thread blocks
    hipLaunchKernelGGL(attn, ga, dim3(512), 0, stream, qb, kb, vb, ob);

    dim3 gg(DD / 64, MTOT / 64);
    hipLaunchKernelGGL(gemm_bias, gg, blk, 0, stream, ob, wow, wob, d_out, flag, 1, 0);
}